// Round 7
// baseline (751.021 us; speedup 1.0000x reference)
//
#include <hip/hip_runtime.h>
#include <hip/hip_bf16.h>
#include <math.h>

#define B_ 16
#define S_ 1024
#define D_ 768
#define H_ 12
#define DH_ 64
#define DFF 3072
#define M_ (B_*S_)   // 16384 token rows

using short8 = __attribute__((ext_vector_type(8))) short;  // 8 bf16 (4 VGPRs)
using f32x4  = __attribute__((ext_vector_type(4))) float;  // MFMA C/D frag

typedef __hip_bfloat16 bf16;

__device__ __forceinline__ bf16 f2b(float f) { return __float2bfloat16(f); }
__device__ __forceinline__ float ldf(const float* p) { return *p; }
__device__ __forceinline__ float ldf(const bf16* p) { return __bfloat162float(*p); }

__device__ __forceinline__ unsigned pkbf(float a, float b) {
  bf16 ha = f2b(a), hb = f2b(b);
  unsigned short ua = *(unsigned short*)&ha, ub = *(unsigned short*)&hb;
  return (unsigned)ua | ((unsigned)ub << 16);
}

__device__ __forceinline__ void gl2lds16(const void* g, void* l) {
  __builtin_amdgcn_global_load_lds((const __attribute__((address_space(1))) void*)g,
                                   (__attribute__((address_space(3))) void*)l, 16, 0, 0);
}

// ---------------------------------------------------------------------------
// Weight prep: fp32 -> bf16 Bt[N][K] (contiguous-k for MFMA B-frags).
// ---------------------------------------------------------------------------
__global__ void conv_t(const float* __restrict__ in, bf16* __restrict__ out, int R, int C) {
  int tid = blockIdx.x * blockDim.x + threadIdx.x;
  if (tid >= R * C) return;
  int r = tid / C, c = tid - r * C;
  out[(size_t)c * R + r] = f2b(in[tid]);
}

__global__ void conv_wqkv(const float* __restrict__ Wq, const float* __restrict__ Wk,
                          const float* __restrict__ Wv, bf16* __restrict__ out) {
  int tid = blockIdx.x * blockDim.x + threadIdx.x;
  const int per = D_ * D_;
  if (tid >= 3 * per) return;
  const float* src = tid < per ? Wq : (tid < 2 * per ? Wk : Wv);
  int base = tid < per ? 0 : (tid < 2 * per ? D_ : 2 * D_);
  int rem = tid < per ? tid : (tid < 2 * per ? tid - per : tid - 2 * per);
  int h   = rem / (D_ * DH_);
  int rem2 = rem - h * (D_ * DH_);
  int d  = rem2 >> 6;
  int dh = rem2 & 63;
  out[(size_t)(base + h * DH_ + dh) * D_ + d] = f2b(src[rem]);
}

// ---------------------------------------------------------------------------
// LayerNorm: one wave per row of 768, fp32 stats, bf16 output.
// ---------------------------------------------------------------------------
template <typename T>
__global__ __launch_bounds__(256) void ln_rows(const T* __restrict__ x,
                                               const float* __restrict__ g,
                                               const float* __restrict__ b,
                                               bf16* __restrict__ out, int rows) {
  int row  = blockIdx.x * 4 + (threadIdx.x >> 6);
  int lane = threadIdx.x & 63;
  if (row >= rows) return;
  const T* xr = x + (size_t)row * D_;
  float v[12];
  float sum = 0.f;
#pragma unroll
  for (int i = 0; i < 12; i++) { v[i] = ldf(xr + lane + i * 64); sum += v[i]; }
#pragma unroll
  for (int off = 32; off > 0; off >>= 1) sum += __shfl_xor(sum, off, 64);
  float mu = sum * (1.0f / 768.0f);
  float var = 0.f;
#pragma unroll
  for (int i = 0; i < 12; i++) { float d = v[i] - mu; var += d * d; }
#pragma unroll
  for (int off = 32; off > 0; off >>= 1) var += __shfl_xor(var, off, 64);
  var *= (1.0f / 768.0f);
  float rs = rsqrtf(var + 1e-5f);
  bf16* orow = out + (size_t)row * D_;
#pragma unroll
  for (int i = 0; i < 12; i++) {
    int c = lane + i * 64;
    orow[c] = f2b((v[i] - mu) * rs * g[c] + b[c]);
  }
}

// ---------------------------------------------------------------------------
// GEMM: C[M,N] = A[M,K](bf16 rm) @ Bt[N,K](bf16), templated epilogue.
// K-loop v3: double-buffered LDS + global_load_lds(16B) direct staging.
//   iter t: issue gl_lds(tile t+1 -> buf[t+1&1]) ; ds_read frags(buf[t&1])
//           ; 16 MFMA ; ONE __syncthreads() (its vmcnt(0) drain overlaps the
//           whole compute phase instead of following the issue immediately).
// No prefetch VGPRs / no ds_writes -> lower VALU + ~4 waves/SIMD occupancy.
// XCD-aware swizzle: id&7 = XCD; 16-row M-band per XCD, walked column-major.
// ---------------------------------------------------------------------------
#define GT 128
#define GK 32

template <int MODE>
__global__ __launch_bounds__(256) void gemm_bt(
    const bf16* __restrict__ A, const bf16* __restrict__ Bt, int K, int ldo,
    const float* __restrict__ bias0, const float* __restrict__ bias1,
    const float* __restrict__ bias2, const float* __restrict__ residf,
    const bf16* __restrict__ residb,
    float* __restrict__ outf, bf16* __restrict__ outb,
    bf16* __restrict__ qo, bf16* __restrict__ ko, bf16* __restrict__ vo) {
  __shared__ __align__(16) bf16 As[2][GT * GK];
  __shared__ __align__(16) bf16 Bs[2][GT * GK];
  const int tid  = threadIdx.x;
  const int w    = tid >> 6, lane = tid & 63;
  const int quad = lane >> 4, ln = lane & 15;
  const int lr   = lane >> 2, lc = (lane & 3) * 8;

  // XCD-aware tile remap (gridDim.y is always 128 here, divisible by 8)
  const int id = blockIdx.y * gridDim.x + blockIdx.x;
  const int bandY = gridDim.y >> 3;          // M-tiles per XCD band
  const int xcd = id & 7, loc = id >> 3;
  const int by = xcd * bandY + (loc % bandY);
  const int bx = loc / bandY;
  const int m0 = by * GT, n0 = bx * GT;
  const int wm = (w >> 1) * 64, wn = (w & 1) * 64;

  f32x4 acc[4][4];
#pragma unroll
  for (int i = 0; i < 4; i++)
#pragma unroll
    for (int j = 0; j < 4; j++)
#pragma unroll
      for (int r = 0; r < 4; r++) acc[i][j][r] = 0.f;

  const int T = K / GK;

  // per-lane global row pointers (wave w stages rows [w*16,w*16+16) + 64)
  const bf16* gA0 = A  + (size_t)(m0 + w * 16 + lr) * K + lc;
  const bf16* gA1 = A  + (size_t)(m0 + 64 + w * 16 + lr) * K + lc;
  const bf16* gB0 = Bt + (size_t)(n0 + w * 16 + lr) * K + lc;
  const bf16* gB1 = Bt + (size_t)(n0 + 64 + w * 16 + lr) * K + lc;

  // prologue: tile 0 -> buf 0
  gl2lds16(gA0, &As[0][(w * 16) * GK]);
  gl2lds16(gA1, &As[0][(64 + w * 16) * GK]);
  gl2lds16(gB0, &Bs[0][(w * 16) * GK]);
  gl2lds16(gB1, &Bs[0][(64 + w * 16) * GK]);
  __syncthreads();

#pragma unroll 2
  for (int t = 0; t < T; t++) {
    if (t + 1 < T) {
      const int kk = (t + 1) * GK;
      bf16* An = As[(t + 1) & 1];
      bf16* Bn = Bs[(t + 1) & 1];
      gl2lds16(gA0 + kk, &An[(w * 16) * GK]);
      gl2lds16(gA1 + kk, &An[(64 + w * 16) * GK]);
      gl2lds16(gB0 + kk, &Bn[(w * 16) * GK]);
      gl2lds16(gB1 + kk, &Bn[(64 + w * 16) * GK]);
    }
    const bf16* Asc = As[t & 1];
    const bf16* Bsc = Bs[t & 1];
    short8 af[4], bfr[4];
#pragma unroll
    for (int u = 0; u < 4; u++) af[u]  = *(const short8*)&Asc[(wm + u * 16 + ln) * GK + quad * 8];
#pragma unroll
    for (int u = 0; u < 4; u++) bfr[u] = *(const short8*)&Bsc[(wn + u * 16 + ln) * GK + quad * 8];
#pragma unroll
    for (int i = 0; i < 4; i++)
#pragma unroll
      for (int j = 0; j < 4; j++)
        acc[i][j] = __builtin_amdgcn_mfma_f32_16x16x32_bf16(af[i], bfr[j], acc[i][j], 0, 0, 0);
    __syncthreads();
  }

#pragma unroll
  for (int i = 0; i < 4; i++) {
#pragma unroll
    for (int j = 0; j < 4; j++) {
#pragma unroll
      for (int r = 0; r < 4; r++) {
        const int m = m0 + wm + i * 16 + quad * 4 + r;
        const int n = n0 + wn + j * 16 + ln;
        float v = acc[i][j][r];
        if (MODE == 0) {
          const int b = m >> 10, s = m & 1023;
          if (n < D_) {
            int h = n >> 6, dh = n & 63;
            qo[(((size_t)(b * H_ + h)) * S_ + s) * DH_ + dh] = f2b(v + bias0[n]);
          } else if (n < 2 * D_) {
            int nn = n - D_; int h = nn >> 6, dh = nn & 63;
            ko[(((size_t)(b * H_ + h)) * S_ + s) * DH_ + dh] = f2b(v + bias1[nn]);
          } else {
            int nn = n - 2 * D_; int h = nn >> 6, dh = nn & 63;
            vo[(((size_t)(b * H_ + h)) * DH_ + dh) * S_ + s] = f2b(v + bias2[nn]);
          }
        } else if (MODE == 1) {
          outb[(size_t)m * ldo + n] = f2b(v + bias0[n] + residf[(size_t)m * ldo + n]);
        } else if (MODE == 2) {
          // tanh-form GELU via hardware exp (|err| vs exact erf-GELU ~1e-3)
          float z = v + bias0[n];
          float u = 0.7978845608028654f * z * (1.0f + 0.044715f * z * z);
          float e = __expf(2.0f * u);
          float th = 1.0f - 2.0f / (e + 1.0f);
          outb[(size_t)m * ldo + n] = f2b(0.5f * z * (1.0f + th));
        } else {
          outf[(size_t)m * ldo + n] =
              v + bias0[n] + __bfloat162float(residb[(size_t)m * ldo + n]);
        }
      }
    }
  }
}

// ---------------------------------------------------------------------------
// Flash attention v2 (S^T formulation, P in-register via shuffles).
// ---------------------------------------------------------------------------
#define KSTR 72    // K LDS row stride (bf16): 64+8, 16B-aligned, conflict-min
#define VSTR 136   // V LDS row stride (bf16): 128+8

__global__ __launch_bounds__(256) void attn(const bf16* __restrict__ qb,
                                            const bf16* __restrict__ kb,
                                            const bf16* __restrict__ vb,
                                            bf16* __restrict__ ctx) {
  __shared__ __align__(16) bf16 Kl[128 * KSTR];  // 18 KiB (also reused for O)
  __shared__ __align__(16) bf16 Vl[64 * VSTR];   // 17 KiB
  const int blk = blockIdx.x;
  const int qt = blk & 7, bh = blk >> 3;
  const int b = bh / H_, h = bh - b * H_;
  const bf16* q  = qb + (size_t)bh * S_ * DH_;
  const bf16* kp = kb + (size_t)bh * S_ * DH_;
  const bf16* vp = vb + (size_t)bh * DH_ * S_;
  const int tid = threadIdx.x;
  const int w = tid >> 6, lane = tid & 63;
  const int quad = lane >> 4, ln = lane & 15;
  const int qs0 = qt * 128 + w * 32;

  const int krow = tid >> 3, kc = tid & 7;    // K: 32 rows/round x 8 chunks
  const int vrow = tid >> 4, vc = tid & 15;   // V: 16 rows/round x 16 chunks

  short8 kpre[4], vpre[4];
#pragma unroll
  for (int r = 0; r < 4; r++) {
    kpre[r] = *(const short8*)&kp[(size_t)(krow + r * 32) * DH_ + kc * 8];
    vpre[r] = *(const short8*)&vp[(size_t)(vrow + r * 16) * S_ + vc * 8];
  }

  short8 qf[2][2];
#pragma unroll
  for (int qg = 0; qg < 2; qg++)
#pragma unroll
    for (int ts = 0; ts < 2; ts++)
      qf[qg][ts] = *(const short8*)&q[(size_t)(qs0 + qg * 16 + ln) * DH_ + ts * 32 + quad * 8];

  f32x4 o[2][4];        // [qg][dt] O^T: dh=dt*16+quad*4+r, q=qg*16+ln
  float mi[2], li[2];
#pragma unroll
  for (int qg = 0; qg < 2; qg++) {
    mi[qg] = -3.0e38f; li[qg] = 0.f;
#pragma unroll
    for (int dt = 0; dt < 4; dt++)
#pragma unroll
      for (int r = 0; r < 4; r++) o[qg][dt][r] = 0.f;
  }

  for (int t0 = 0; t0 < S_; t0 += 128) {
    __syncthreads();
#pragma unroll
    for (int r = 0; r < 4; r++) {
      *(short8*)&Kl[(krow + r * 32) * KSTR + kc * 8] = kpre[r];
      *(short8*)&Vl[(vrow + r * 16) * VSTR + vc * 8] = vpre[r];
    }
    const int tn = (t0 + 128) & (S_ - 1);
#pragma unroll
    for (int r = 0; r < 4; r++) {
      kpre[r] = *(const short8*)&kp[(size_t)(tn + krow + r * 32) * DH_ + kc * 8];
      vpre[r] = *(const short8*)&vp[(size_t)(vrow + r * 16) * S_ + tn + vc * 8];
    }
    __syncthreads();

    f32x4 sa[2][8];
#pragma unroll
    for (int qg = 0; qg < 2; qg++)
#pragma unroll
      for (int tt = 0; tt < 8; tt++)
#pragma unroll
        for (int r = 0; r < 4; r++) sa[qg][tt][r] = 0.f;
#pragma unroll
    for (int tt = 0; tt < 8; tt++) {
      short8 ka0 = *(const short8*)&Kl[(tt * 16 + ln) * KSTR + quad * 8];
      short8 ka1 = *(const short8*)&Kl[(tt * 16 + ln) * KSTR + 32 + quad * 8];
#pragma unroll
      for (int qg = 0; qg < 2; qg++) {
        sa[qg][tt] = __builtin_amdgcn_mfma_f32_16x16x32_bf16(ka0, qf[qg][0], sa[qg][tt], 0, 0, 0);
        sa[qg][tt] = __builtin_amdgcn_mfma_f32_16x16x32_bf16(ka1, qf[qg][1], sa[qg][tt], 0, 0, 0);
      }
    }

    unsigned pk[2][8][2];
#pragma unroll
    for (int qg = 0; qg < 2; qg++) {
      float mx = -3.0e38f;
#pragma unroll
      for (int tt = 0; tt < 8; tt++)
#pragma unroll
        for (int r = 0; r < 4; r++) {
          float s = sa[qg][tt][r] * 0.125f;
          sa[qg][tt][r] = s;
          mx = fmaxf(mx, s);
        }
      mx = fmaxf(mx, __shfl_xor(mx, 16, 64));
      mx = fmaxf(mx, __shfl_xor(mx, 32, 64));
      float mnew = fmaxf(mi[qg], mx);
      float alpha = __expf(mi[qg] - mnew);
      float rs = 0.f;
#pragma unroll
      for (int tt = 0; tt < 8; tt++) {
        float p0 = __expf(sa[qg][tt][0] - mnew);
        float p1 = __expf(sa[qg][tt][1] - mnew);
        float p2 = __expf(sa[qg][tt][2] - mnew);
        float p3 = __expf(sa[qg][tt][3] - mnew);
        rs += (p0 + p1) + (p2 + p3);
        pk[qg][tt][0] = pkbf(p0, p1);
        pk[qg][tt][1] = pkbf(p2, p3);
      }
      rs += __shfl_xor(rs, 16, 64);
      rs += __shfl_xor(rs, 32, 64);
      li[qg] = li[qg] * alpha + rs;
      mi[qg] = mnew;
#pragma unroll
      for (int dt = 0; dt < 4; dt++)
#pragma unroll
        for (int r = 0; r < 4; r++) o[qg][dt][r] *= alpha;
    }

    const int src = (quad & 1) * 32 + ln;
    const bool hi = quad >= 2;
#pragma unroll
    for (int tt32 = 0; tt32 < 4; tt32++) {
#pragma unroll
      for (int qg = 0; qg < 2; qg++) {
        unsigned e0 = pk[qg][2 * tt32][0],     e1 = pk[qg][2 * tt32][1];
        unsigned o0 = pk[qg][2 * tt32 + 1][0], o1 = pk[qg][2 * tt32 + 1][1];
        unsigned a0 = __shfl((int)e0, src, 64),      b0 = __shfl((int)o0, src, 64);
        unsigned a1 = __shfl((int)e1, src, 64),      b1 = __shfl((int)o1, src, 64);
        unsigned a2 = __shfl((int)e0, src + 16, 64), b2 = __shfl((int)o0, src + 16, 64);
        unsigned a3 = __shfl((int)e1, src + 16, 64), b3 = __shfl((int)o1, src + 16, 64);
        union { unsigned u[4]; short8 s; } fr;
        fr.u[0] = hi ? b0 : a0;
        fr.u[1] = hi ? b1 : a1;
        fr.u[2] = hi ? b2 : a2;
        fr.u[3] = hi ? b3 : a3;
#pragma unroll
        for (int dt = 0; dt < 4; dt++) {
          short8 va = *(const short8*)&Vl[(dt * 16 + ln) * VSTR + tt32 * 32 + quad * 8];
          o[qg][dt] = __builtin_amdgcn_mfma_f32_16x16x32_bf16(va, fr.s, o[qg][dt], 0, 0, 0);
        }
      }
    }
  }

  __syncthreads();
  bf16* Ol = Kl;
#pragma unroll
  for (int qg = 0; qg < 2; qg++) {
    float inv = 1.0f / li[qg];
#pragma unroll
    for (int dt = 0; dt < 4; dt++)
#pragma unroll
      for (int r = 0; r < 4; r++)
        Ol[(w * 32 + qg * 16 + ln) * KSTR + dt * 16 + quad * 4 + r] = f2b(o[qg][dt][r] * inv);
  }
  __syncthreads();
  const int orow = tid >> 3, oc = tid & 7;
#pragma unroll
  for (int rd = 0; rd < 4; rd++) {
    int row = orow + rd * 32;
    short8 val = *(const short8*)&Ol[row * KSTR + oc * 8];
    *(short8*)&ctx[((size_t)(b * S_ + qt * 128 + row)) * D_ + h * DH_ + oc * 8] = val;
  }
}

// ---------------------------------------------------------------------------
extern "C" void kernel_launch(void* const* d_in, const int* in_sizes, int n_in,
                              void* d_out, int out_size, void* d_ws, size_t ws_size,
                              hipStream_t stream) {
  const float* x    = (const float*)d_in[0];
  const float* ln1g = (const float*)d_in[1];
  const float* ln1b = (const float*)d_in[2];
  const float* Wq   = (const float*)d_in[3];
  const float* bq   = (const float*)d_in[4];
  const float* Wk   = (const float*)d_in[5];
  const float* bk   = (const float*)d_in[6];
  const float* Wv   = (const float*)d_in[7];
  const float* bv   = (const float*)d_in[8];
  const float* Wo   = (const float*)d_in[9];
  const float* bo   = (const float*)d_in[10];
  const float* ln2g = (const float*)d_in[11];
  const float* ln2b = (const float*)d_in[12];
  const float* W1   = (const float*)d_in[13];
  const float* b1   = (const float*)d_in[14];
  const float* W2   = (const float*)d_in[15];
  const float* b2   = (const float*)d_in[16];

  // ------- workspace layout (~158 MiB total; a1 aliases q/k/v/ctx) -------
  char* ws = (char*)d_ws;
  const size_t SZ_MD = (size_t)M_ * D_ * 2;            // 24 MiB (bf16 [M,D])
  size_t off = 0;
  bf16* wqkvt = (bf16*)(ws + off); off += (size_t)3 * D_ * D_ * 2;
  bf16* wot   = (bf16*)(ws + off); off += (size_t)D_ * D_ * 2;
  bf16* w1t   = (bf16*)(ws + off); off += (size_t)DFF * D_ * 2;
  bf16* w2t   = (bf16*)(ws + off); off += (size_t)D_ * DFF * 2;
  bf16* h     = (bf16*)(ws + off); off += SZ_MD;
  bf16* x1    = (bf16*)(ws + off); off += SZ_MD;
  char* unionbase = ws + off;                          // 96 MiB union region
  bf16* qbuf = (bf16*)(unionbase);
  bf16* kbuf = (bf16*)(unionbase + SZ_MD);
  bf16* vbuf = (bf16*)(unionbase + 2 * SZ_MD);
  bf16* ctx  = (bf16*)(unionbase + 3 * SZ_MD);
  bf16* a1   = (bf16*)(unionbase);                     // [M,DFF] == 4*SZ_MD

  // weight prep + LN1
  conv_wqkv<<<(3 * D_ * D_ + 255) / 256, 256, 0, stream>>>(Wq, Wk, Wv, wqkvt);
  conv_t<<<(D_ * D_ + 255) / 256, 256, 0, stream>>>(Wo, wot, D_, D_);
  conv_t<<<(D_ * DFF + 255) / 256, 256, 0, stream>>>(W1, w1t, D_, DFF);
  conv_t<<<(D_ * DFF + 255) / 256, 256, 0, stream>>>(W2, w2t, DFF, D_);
  ln_rows<float><<<M_ / 4, 256, 0, stream>>>(x, ln1g, ln1b, h, M_);

  // QKV projection (scatter epilogue)
  gemm_bt<0><<<dim3(3 * D_ / GT, M_ / GT), 256, 0, stream>>>(
      h, wqkvt, D_, 0, bq, bk, bv, nullptr, nullptr, nullptr, nullptr,
      qbuf, kbuf, vbuf);

  // attention
  attn<<<B_ * H_ * (S_ / 128), 256, 0, stream>>>(qbuf, kbuf, vbuf, ctx);

  // Wo + bias + fp32 residual(x) -> x1 (bf16)
  gemm_bt<1><<<dim3(D_ / GT, M_ / GT), 256, 0, stream>>>(
      ctx, wot, D_, D_, bo, nullptr, nullptr, x, nullptr, nullptr, x1,
      nullptr, nullptr, nullptr);

  // LN2 -> h ; W1 + GELU -> a1 (overwrites q/k/v/ctx region, all dead now)
  ln_rows<bf16><<<M_ / 4, 256, 0, stream>>>(x1, ln2g, ln2b, h, M_);
  gemm_bt<2><<<dim3(DFF / GT, M_ / GT), 256, 0, stream>>>(
      h, w1t, D_, DFF, b1, nullptr, nullptr, nullptr, nullptr, nullptr, a1,
      nullptr, nullptr, nullptr);

  // W2 + bias + bf16 residual(x1) -> d_out (fp32)
  gemm_bt<3><<<dim3(D_ / GT, M_ / GT), 256, 0, stream>>>(
      a1, w2t, DFF, D_, b2, nullptr, nullptr, nullptr, x1, (float*)d_out,
      nullptr, nullptr, nullptr, nullptr);
}

// Round 8
// 663.685 us; speedup vs baseline: 1.1316x; 1.1316x over previous
//
#include <hip/hip_runtime.h>
#include <hip/hip_bf16.h>
#include <math.h>

#define B_ 16
#define S_ 1024
#define D_ 768
#define H_ 12
#define DH_ 64
#define DFF 3072
#define M_ (B_*S_)   // 16384 token rows

using short8 = __attribute__((ext_vector_type(8))) short;  // 8 bf16 (4 VGPRs)
using f32x4  = __attribute__((ext_vector_type(4))) float;  // MFMA C/D frag

typedef __hip_bfloat16 bf16;

__device__ __forceinline__ bf16 f2b(float f) { return __float2bfloat16(f); }
__device__ __forceinline__ float ldf(const float* p) { return *p; }
__device__ __forceinline__ float ldf(const bf16* p) { return __bfloat162float(*p); }

__device__ __forceinline__ unsigned pkbf(float a, float b) {
  bf16 ha = f2b(a), hb = f2b(b);
  unsigned short ua = *(unsigned short*)&ha, ub = *(unsigned short*)&hb;
  return (unsigned)ua | ((unsigned)ub << 16);
}

// ---------------------------------------------------------------------------
// Weight prep: fp32 -> bf16 Bt[N][K] (contiguous-k for MFMA B-frags).
// ---------------------------------------------------------------------------
__global__ void conv_t(const float* __restrict__ in, bf16* __restrict__ out, int R, int C) {
  int tid = blockIdx.x * blockDim.x + threadIdx.x;
  if (tid >= R * C) return;
  int r = tid / C, c = tid - r * C;
  out[(size_t)c * R + r] = f2b(in[tid]);
}

__global__ void conv_wqkv(const float* __restrict__ Wq, const float* __restrict__ Wk,
                          const float* __restrict__ Wv, bf16* __restrict__ out) {
  int tid = blockIdx.x * blockDim.x + threadIdx.x;
  const int per = D_ * D_;
  if (tid >= 3 * per) return;
  const float* src = tid < per ? Wq : (tid < 2 * per ? Wk : Wv);
  int base = tid < per ? 0 : (tid < 2 * per ? D_ : 2 * D_);
  int rem = tid < per ? tid : (tid < 2 * per ? tid - per : tid - 2 * per);
  int h   = rem / (D_ * DH_);
  int rem2 = rem - h * (D_ * DH_);
  int d  = rem2 >> 6;
  int dh = rem2 & 63;
  out[(size_t)(base + h * DH_ + dh) * D_ + d] = f2b(src[rem]);
}

// ---------------------------------------------------------------------------
// LayerNorm: one wave per row of 768, fp32 stats, bf16 output.
// ---------------------------------------------------------------------------
template <typename T>
__global__ __launch_bounds__(256) void ln_rows(const T* __restrict__ x,
                                               const float* __restrict__ g,
                                               const float* __restrict__ b,
                                               bf16* __restrict__ out, int rows) {
  int row  = blockIdx.x * 4 + (threadIdx.x >> 6);
  int lane = threadIdx.x & 63;
  if (row >= rows) return;
  const T* xr = x + (size_t)row * D_;
  float v[12];
  float sum = 0.f;
#pragma unroll
  for (int i = 0; i < 12; i++) { v[i] = ldf(xr + lane + i * 64); sum += v[i]; }
#pragma unroll
  for (int off = 32; off > 0; off >>= 1) sum += __shfl_xor(sum, off, 64);
  float mu = sum * (1.0f / 768.0f);
  float var = 0.f;
#pragma unroll
  for (int i = 0; i < 12; i++) { float d = v[i] - mu; var += d * d; }
#pragma unroll
  for (int off = 32; off > 0; off >>= 1) var += __shfl_xor(var, off, 64);
  var *= (1.0f / 768.0f);
  float rs = rsqrtf(var + 1e-5f);
  bf16* orow = out + (size_t)row * D_;
#pragma unroll
  for (int i = 0; i < 12; i++) {
    int c = lane + i * 64;
    orow[c] = f2b((v[i] - mu) * rs * g[c] + b[c]);
  }
}

// ---------------------------------------------------------------------------
// GEMM: C[M,N] = A[M,K](bf16 rm) @ Bt[N,K](bf16), templated epilogue.
// Round-6 staging (register prefetch + LDS dbuf + single barrier) with
// 512 threads / 8 waves per 128x128 tile; wave = 64x32 (4x2 acc, 32 AGPR).
// Halved per-wave serial chain + ~2x waves/SIMD for latency hiding.
// XCD-aware swizzle: id&7 = XCD; 16-row M-band per XCD, walked column-major.
// ---------------------------------------------------------------------------
#define GT 128
#define GK 32

template <int MODE>
__global__ __launch_bounds__(512, 4) void gemm_bt(
    const bf16* __restrict__ A, const bf16* __restrict__ Bt, int K, int ldo,
    const float* __restrict__ bias0, const float* __restrict__ bias1,
    const float* __restrict__ bias2, const float* __restrict__ residf,
    const bf16* __restrict__ residb,
    float* __restrict__ outf, bf16* __restrict__ outb,
    bf16* __restrict__ qo, bf16* __restrict__ ko, bf16* __restrict__ vo) {
  __shared__ __align__(16) bf16 As[2][GT * GK];
  __shared__ __align__(16) bf16 Bs[2][GT * GK];
  const int tid  = threadIdx.x;
  const int w    = tid >> 6, lane = tid & 63;
  const int quad = lane >> 4, ln = lane & 15;

  // XCD-aware tile remap (gridDim.y is always 128 here, divisible by 8)
  const int id = blockIdx.y * gridDim.x + blockIdx.x;
  const int bandY = gridDim.y >> 3;          // M-tiles per XCD band
  const int xcd = id & 7, loc = id >> 3;
  const int by = xcd * bandY + (loc % bandY);
  const int bx = loc / bandY;
  const int m0 = by * GT, n0 = bx * GT;
  const int wm = (w >> 2) * 64, wn = (w & 3) * 32;   // wave tile 64x32

  // staging mapping: thread covers one row's 16B chunk per matrix
  const int ar = tid >> 2;
  const int ac = (tid & 3) * 8;

  f32x4 acc[4][2];
#pragma unroll
  for (int i = 0; i < 4; i++)
#pragma unroll
    for (int j = 0; j < 2; j++)
#pragma unroll
      for (int r = 0; r < 4; r++) acc[i][j][r] = 0.f;

  const int T = K / GK;

  // prologue: tile 0 -> LDS buf0; tile 1 -> regs
  short8 apre, bpre;
  apre = *(const short8*)&A[(size_t)(m0 + ar) * K + ac];
  bpre = *(const short8*)&Bt[(size_t)(n0 + ar) * K + ac];
  *(short8*)&As[0][ar * GK + ac] = apre;
  *(short8*)&Bs[0][ar * GK + ac] = bpre;
  apre = *(const short8*)&A[(size_t)(m0 + ar) * K + GK + ac];
  bpre = *(const short8*)&Bt[(size_t)(n0 + ar) * K + GK + ac];
  __syncthreads();

#pragma unroll 2
  for (int t = 0; t < T; t++) {
    const bf16* Asc = As[t & 1];
    const bf16* Bsc = Bs[t & 1];
    short8 af[4], bfr[2];
#pragma unroll
    for (int u = 0; u < 4; u++) af[u]  = *(const short8*)&Asc[(wm + u * 16 + ln) * GK + quad * 8];
#pragma unroll
    for (int u = 0; u < 2; u++) bfr[u] = *(const short8*)&Bsc[(wn + u * 16 + ln) * GK + quad * 8];
#pragma unroll
    for (int i = 0; i < 4; i++)
#pragma unroll
      for (int j = 0; j < 2; j++)
        acc[i][j] = __builtin_amdgcn_mfma_f32_16x16x32_bf16(af[i], bfr[j], acc[i][j], 0, 0, 0);
    if (t + 1 < T) {
      bf16* Asn = As[(t + 1) & 1];
      bf16* Bsn = Bs[(t + 1) & 1];
      *(short8*)&Asn[ar * GK + ac] = apre;
      *(short8*)&Bsn[ar * GK + ac] = bpre;
      const int kn = (t + 2 < T) ? (t + 2) * GK : 0;  // wrap: valid, unused
      apre = *(const short8*)&A[(size_t)(m0 + ar) * K + kn + ac];
      bpre = *(const short8*)&Bt[(size_t)(n0 + ar) * K + kn + ac];
      __syncthreads();
    }
  }

#pragma unroll
  for (int i = 0; i < 4; i++) {
#pragma unroll
    for (int j = 0; j < 2; j++) {
#pragma unroll
      for (int r = 0; r < 4; r++) {
        const int m = m0 + wm + i * 16 + quad * 4 + r;
        const int n = n0 + wn + j * 16 + ln;
        float v = acc[i][j][r];
        if (MODE == 0) {
          const int b = m >> 10, s = m & 1023;
          if (n < D_) {
            int h = n >> 6, dh = n & 63;
            qo[(((size_t)(b * H_ + h)) * S_ + s) * DH_ + dh] = f2b(v + bias0[n]);
          } else if (n < 2 * D_) {
            int nn = n - D_; int h = nn >> 6, dh = nn & 63;
            ko[(((size_t)(b * H_ + h)) * S_ + s) * DH_ + dh] = f2b(v + bias1[nn]);
          } else {
            int nn = n - 2 * D_; int h = nn >> 6, dh = nn & 63;
            vo[(((size_t)(b * H_ + h)) * DH_ + dh) * S_ + s] = f2b(v + bias2[nn]);
          }
        } else if (MODE == 1) {
          outb[(size_t)m * ldo + n] = f2b(v + bias0[n] + residf[(size_t)m * ldo + n]);
        } else if (MODE == 2) {
          // tanh-form GELU via hardware exp (|err| vs exact erf-GELU ~1e-3)
          float z = v + bias0[n];
          float u = 0.7978845608028654f * z * (1.0f + 0.044715f * z * z);
          float e = __expf(2.0f * u);
          float th = 1.0f - 2.0f / (e + 1.0f);
          outb[(size_t)m * ldo + n] = f2b(0.5f * z * (1.0f + th));
        } else {
          outf[(size_t)m * ldo + n] =
              v + bias0[n] + __bfloat162float(residb[(size_t)m * ldo + n]);
        }
      }
    }
  }
}

// ---------------------------------------------------------------------------
// Flash attention v2 (S^T formulation, P in-register via shuffles).
// ---------------------------------------------------------------------------
#define KSTR 72    // K LDS row stride (bf16): 64+8, 16B-aligned, conflict-min
#define VSTR 136   // V LDS row stride (bf16): 128+8

__global__ __launch_bounds__(256) void attn(const bf16* __restrict__ qb,
                                            const bf16* __restrict__ kb,
                                            const bf16* __restrict__ vb,
                                            bf16* __restrict__ ctx) {
  __shared__ __align__(16) bf16 Kl[128 * KSTR];  // 18 KiB (also reused for O)
  __shared__ __align__(16) bf16 Vl[64 * VSTR];   // 17 KiB
  const int blk = blockIdx.x;
  const int qt = blk & 7, bh = blk >> 3;
  const int b = bh / H_, h = bh - b * H_;
  const bf16* q  = qb + (size_t)bh * S_ * DH_;
  const bf16* kp = kb + (size_t)bh * S_ * DH_;
  const bf16* vp = vb + (size_t)bh * DH_ * S_;
  const int tid = threadIdx.x;
  const int w = tid >> 6, lane = tid & 63;
  const int quad = lane >> 4, ln = lane & 15;
  const int qs0 = qt * 128 + w * 32;

  const int krow = tid >> 3, kc = tid & 7;    // K: 32 rows/round x 8 chunks
  const int vrow = tid >> 4, vc = tid & 15;   // V: 16 rows/round x 16 chunks

  short8 kpre[4], vpre[4];
#pragma unroll
  for (int r = 0; r < 4; r++) {
    kpre[r] = *(const short8*)&kp[(size_t)(krow + r * 32) * DH_ + kc * 8];
    vpre[r] = *(const short8*)&vp[(size_t)(vrow + r * 16) * S_ + vc * 8];
  }

  short8 qf[2][2];
#pragma unroll
  for (int qg = 0; qg < 2; qg++)
#pragma unroll
    for (int ts = 0; ts < 2; ts++)
      qf[qg][ts] = *(const short8*)&q[(size_t)(qs0 + qg * 16 + ln) * DH_ + ts * 32 + quad * 8];

  f32x4 o[2][4];        // [qg][dt] O^T: dh=dt*16+quad*4+r, q=qg*16+ln
  float mi[2], li[2];
#pragma unroll
  for (int qg = 0; qg < 2; qg++) {
    mi[qg] = -3.0e38f; li[qg] = 0.f;
#pragma unroll
    for (int dt = 0; dt < 4; dt++)
#pragma unroll
      for (int r = 0; r < 4; r++) o[qg][dt][r] = 0.f;
  }

  for (int t0 = 0; t0 < S_; t0 += 128) {
    __syncthreads();
#pragma unroll
    for (int r = 0; r < 4; r++) {
      *(short8*)&Kl[(krow + r * 32) * KSTR + kc * 8] = kpre[r];
      *(short8*)&Vl[(vrow + r * 16) * VSTR + vc * 8] = vpre[r];
    }
    const int tn = (t0 + 128) & (S_ - 1);
#pragma unroll
    for (int r = 0; r < 4; r++) {
      kpre[r] = *(const short8*)&kp[(size_t)(tn + krow + r * 32) * DH_ + kc * 8];
      vpre[r] = *(const short8*)&vp[(size_t)(vrow + r * 16) * S_ + tn + vc * 8];
    }
    __syncthreads();

    f32x4 sa[2][8];
#pragma unroll
    for (int qg = 0; qg < 2; qg++)
#pragma unroll
      for (int tt = 0; tt < 8; tt++)
#pragma unroll
        for (int r = 0; r < 4; r++) sa[qg][tt][r] = 0.f;
#pragma unroll
    for (int tt = 0; tt < 8; tt++) {
      short8 ka0 = *(const short8*)&Kl[(tt * 16 + ln) * KSTR + quad * 8];
      short8 ka1 = *(const short8*)&Kl[(tt * 16 + ln) * KSTR + 32 + quad * 8];
#pragma unroll
      for (int qg = 0; qg < 2; qg++) {
        sa[qg][tt] = __builtin_amdgcn_mfma_f32_16x16x32_bf16(ka0, qf[qg][0], sa[qg][tt], 0, 0, 0);
        sa[qg][tt] = __builtin_amdgcn_mfma_f32_16x16x32_bf16(ka1, qf[qg][1], sa[qg][tt], 0, 0, 0);
      }
    }

    unsigned pk[2][8][2];
#pragma unroll
    for (int qg = 0; qg < 2; qg++) {
      float mx = -3.0e38f;
#pragma unroll
      for (int tt = 0; tt < 8; tt++)
#pragma unroll
        for (int r = 0; r < 4; r++) {
          float s = sa[qg][tt][r] * 0.125f;
          sa[qg][tt][r] = s;
          mx = fmaxf(mx, s);
        }
      mx = fmaxf(mx, __shfl_xor(mx, 16, 64));
      mx = fmaxf(mx, __shfl_xor(mx, 32, 64));
      float mnew = fmaxf(mi[qg], mx);
      float alpha = __expf(mi[qg] - mnew);
      float rs = 0.f;
#pragma unroll
      for (int tt = 0; tt < 8; tt++) {
        float p0 = __expf(sa[qg][tt][0] - mnew);
        float p1 = __expf(sa[qg][tt][1] - mnew);
        float p2 = __expf(sa[qg][tt][2] - mnew);
        float p3 = __expf(sa[qg][tt][3] - mnew);
        rs += (p0 + p1) + (p2 + p3);
        pk[qg][tt][0] = pkbf(p0, p1);
        pk[qg][tt][1] = pkbf(p2, p3);
      }
      rs += __shfl_xor(rs, 16, 64);
      rs += __shfl_xor(rs, 32, 64);
      li[qg] = li[qg] * alpha + rs;
      mi[qg] = mnew;
#pragma unroll
      for (int dt = 0; dt < 4; dt++)
#pragma unroll
        for (int r = 0; r < 4; r++) o[qg][dt][r] *= alpha;
    }

    const int src = (quad & 1) * 32 + ln;
    const bool hi = quad >= 2;
#pragma unroll
    for (int tt32 = 0; tt32 < 4; tt32++) {
#pragma unroll
      for (int qg = 0; qg < 2; qg++) {
        unsigned e0 = pk[qg][2 * tt32][0],     e1 = pk[qg][2 * tt32][1];
        unsigned o0 = pk[qg][2 * tt32 + 1][0], o1 = pk[qg][2 * tt32 + 1][1];
        unsigned a0 = __shfl((int)e0, src, 64),      b0 = __shfl((int)o0, src, 64);
        unsigned a1 = __shfl((int)e1, src, 64),      b1 = __shfl((int)o1, src, 64);
        unsigned a2 = __shfl((int)e0, src + 16, 64), b2 = __shfl((int)o0, src + 16, 64);
        unsigned a3 = __shfl((int)e1, src + 16, 64), b3 = __shfl((int)o1, src + 16, 64);
        union { unsigned u[4]; short8 s; } fr;
        fr.u[0] = hi ? b0 : a0;
        fr.u[1] = hi ? b1 : a1;
        fr.u[2] = hi ? b2 : a2;
        fr.u[3] = hi ? b3 : a3;
#pragma unroll
        for (int dt = 0; dt < 4; dt++) {
          short8 va = *(const short8*)&Vl[(dt * 16 + ln) * VSTR + tt32 * 32 + quad * 8];
          o[qg][dt] = __builtin_amdgcn_mfma_f32_16x16x32_bf16(va, fr.s, o[qg][dt], 0, 0, 0);
        }
      }
    }
  }

  __syncthreads();
  bf16* Ol = Kl;
#pragma unroll
  for (int qg = 0; qg < 2; qg++) {
    float inv = 1.0f / li[qg];
#pragma unroll
    for (int dt = 0; dt < 4; dt++)
#pragma unroll
      for (int r = 0; r < 4; r++)
        Ol[(w * 32 + qg * 16 + ln) * KSTR + dt * 16 + quad * 4 + r] = f2b(o[qg][dt][r] * inv);
  }
  __syncthreads();
  const int orow = tid >> 3, oc = tid & 7;
#pragma unroll
  for (int rd = 0; rd < 4; rd++) {
    int row = orow + rd * 32;
    short8 val = *(const short8*)&Ol[row * KSTR + oc * 8];
    *(short8*)&ctx[((size_t)(b * S_ + qt * 128 + row)) * D_ + h * DH_ + oc * 8] = val;
  }
}

// ---------------------------------------------------------------------------
extern "C" void kernel_launch(void* const* d_in, const int* in_sizes, int n_in,
                              void* d_out, int out_size, void* d_ws, size_t ws_size,
                              hipStream_t stream) {
  const float* x    = (const float*)d_in[0];
  const float* ln1g = (const float*)d_in[1];
  const float* ln1b = (const float*)d_in[2];
  const float* Wq   = (const float*)d_in[3];
  const float* bq   = (const float*)d_in[4];
  const float* Wk   = (const float*)d_in[5];
  const float* bk   = (const float*)d_in[6];
  const float* Wv   = (const float*)d_in[7];
  const float* bv   = (const float*)d_in[8];
  const float* Wo   = (const float*)d_in[9];
  const float* bo   = (const float*)d_in[10];
  const float* ln2g = (const float*)d_in[11];
  const float* ln2b = (const float*)d_in[12];
  const float* W1   = (const float*)d_in[13];
  const float* b1   = (const float*)d_in[14];
  const float* W2   = (const float*)d_in[15];
  const float* b2   = (const float*)d_in[16];

  // ------- workspace layout (~158 MiB total; a1 aliases q/k/v/ctx) -------
  char* ws = (char*)d_ws;
  const size_t SZ_MD = (size_t)M_ * D_ * 2;            // 24 MiB (bf16 [M,D])
  size_t off = 0;
  bf16* wqkvt = (bf16*)(ws + off); off += (size_t)3 * D_ * D_ * 2;
  bf16* wot   = (bf16*)(ws + off); off += (size_t)D_ * D_ * 2;
  bf16* w1t   = (bf16*)(ws + off); off += (size_t)DFF * D_ * 2;
  bf16* w2t   = (bf16*)(ws + off); off += (size_t)D_ * DFF * 2;
  bf16* h     = (bf16*)(ws + off); off += SZ_MD;
  bf16* x1    = (bf16*)(ws + off); off += SZ_MD;
  char* unionbase = ws + off;                          // 96 MiB union region
  bf16* qbuf = (bf16*)(unionbase);
  bf16* kbuf = (bf16*)(unionbase + SZ_MD);
  bf16* vbuf = (bf16*)(unionbase + 2 * SZ_MD);
  bf16* ctx  = (bf16*)(unionbase + 3 * SZ_MD);
  bf16* a1   = (bf16*)(unionbase);                     // [M,DFF] == 4*SZ_MD

  // weight prep + LN1
  conv_wqkv<<<(3 * D_ * D_ + 255) / 256, 256, 0, stream>>>(Wq, Wk, Wv, wqkvt);
  conv_t<<<(D_ * D_ + 255) / 256, 256, 0, stream>>>(Wo, wot, D_, D_);
  conv_t<<<(D_ * DFF + 255) / 256, 256, 0, stream>>>(W1, w1t, D_, DFF);
  conv_t<<<(D_ * DFF + 255) / 256, 256, 0, stream>>>(W2, w2t, DFF, D_);
  ln_rows<float><<<M_ / 4, 256, 0, stream>>>(x, ln1g, ln1b, h, M_);

  // QKV projection (scatter epilogue)
  gemm_bt<0><<<dim3(3 * D_ / GT, M_ / GT), 512, 0, stream>>>(
      h, wqkvt, D_, 0, bq, bk, bv, nullptr, nullptr, nullptr, nullptr,
      qbuf, kbuf, vbuf);

  // attention
  attn<<<B_ * H_ * (S_ / 128), 256, 0, stream>>>(qbuf, kbuf, vbuf, ctx);

  // Wo + bias + fp32 residual(x) -> x1 (bf16)
  gemm_bt<1><<<dim3(D_ / GT, M_ / GT), 512, 0, stream>>>(
      ctx, wot, D_, D_, bo, nullptr, nullptr, x, nullptr, nullptr, x1,
      nullptr, nullptr, nullptr);

  // LN2 -> h ; W1 + GELU -> a1 (overwrites q/k/v/ctx region, all dead now)
  ln_rows<bf16><<<M_ / 4, 256, 0, stream>>>(x1, ln2g, ln2b, h, M_);
  gemm_bt<2><<<dim3(DFF / GT, M_ / GT), 512, 0, stream>>>(
      h, w1t, D_, DFF, b1, nullptr, nullptr, nullptr, nullptr, nullptr, a1,
      nullptr, nullptr, nullptr);

  // W2 + bias + bf16 residual(x1) -> d_out (fp32)
  gemm_bt<3><<<dim3(D_ / GT, M_ / GT), 512, 0, stream>>>(
      a1, w2t, DFF, D_, b2, nullptr, nullptr, nullptr, x1, (float*)d_out,
      nullptr, nullptr, nullptr, nullptr);
}